// Round 1
// baseline (78.478 us; speedup 1.0000x reference)
//
#include <hip/hip_runtime.h>
#include <math.h>

#define IN_C 64
#define OUT_C 16

// ---------------------------------------------------------------------------
// Kernel 1: h = x @ W_lin + b_lin      [N,64] x [64,16] -> [N,16]
// One thread per node. W_lin/b_lin staged in LDS (broadcast reads).
// ---------------------------------------------------------------------------
__global__ __launch_bounds__(256) void node_linear_kernel(
    const float* __restrict__ x, const float* __restrict__ W_lin,
    const float* __restrict__ b_lin, float* __restrict__ h, int N)
{
    __shared__ float sW[IN_C * OUT_C];   // 1024 floats = 4 KB
    __shared__ float sb[OUT_C];
    for (int i = threadIdx.x; i < IN_C * OUT_C; i += blockDim.x) sW[i] = W_lin[i];
    if (threadIdx.x < OUT_C) sb[threadIdx.x] = b_lin[threadIdx.x];
    __syncthreads();

    int n = blockIdx.x * blockDim.x + threadIdx.x;
    if (n >= N) return;

    float acc[OUT_C];
    #pragma unroll
    for (int j = 0; j < OUT_C; j++) acc[j] = sb[j];

    const float4* xr = (const float4*)(x + (size_t)n * IN_C);
    #pragma unroll
    for (int k4 = 0; k4 < IN_C / 4; k4++) {
        float4 xv = xr[k4];
        float xs[4] = {xv.x, xv.y, xv.z, xv.w};
        #pragma unroll
        for (int kk = 0; kk < 4; kk++) {
            const int k = k4 * 4 + kk;
            const float4* wrow = (const float4*)(sW + k * OUT_C);
            #pragma unroll
            for (int jq = 0; jq < 4; jq++) {
                float4 wv = wrow[jq];
                acc[jq * 4 + 0] = fmaf(xs[kk], wv.x, acc[jq * 4 + 0]);
                acc[jq * 4 + 1] = fmaf(xs[kk], wv.y, acc[jq * 4 + 1]);
                acc[jq * 4 + 2] = fmaf(xs[kk], wv.z, acc[jq * 4 + 2]);
                acc[jq * 4 + 3] = fmaf(xs[kk], wv.w, acc[jq * 4 + 3]);
            }
        }
    }

    float4* hr = (float4*)(h + (size_t)n * OUT_C);
    #pragma unroll
    for (int jq = 0; jq < 4; jq++) {
        float4 o;
        o.x = acc[jq * 4 + 0]; o.y = acc[jq * 4 + 1];
        o.z = acc[jq * 4 + 2]; o.w = acc[jq * 4 + 3];
        hr[jq] = o;
    }
}

// ---------------------------------------------------------------------------
// Kernel 2: per-edge fused pipeline. One thread per edge.
//   ea   = edge_attr[e] @ W_edge + b_edge                  (16)
//   nv   = h[col[e]]                                       (16)
//   score(c) = P*c + Q + sum_j s_j * |c*w1_j + b1_j|       (abs-trick MLP)
//   attn = softmax over the 32 scores
//   out[e][i] = nv[i>>1] * attn[i]
// ---------------------------------------------------------------------------
__global__ __launch_bounds__(256) void edge_attn_kernel(
    const float* __restrict__ edge_attr, const int* __restrict__ col,
    const float* __restrict__ h,
    const float* __restrict__ W_edge, const float* __restrict__ b_edge,
    const float* __restrict__ w1, const float* __restrict__ b1,
    const float* __restrict__ w2, const float* __restrict__ b2,
    float* __restrict__ out, int E)
{
    __shared__ float sWe[8 * OUT_C];   // 128 floats
    __shared__ float sbe[OUT_C];
    for (int i = threadIdx.x; i < 8 * OUT_C; i += blockDim.x) sWe[i] = W_edge[i];
    if (threadIdx.x < OUT_C) sbe[threadIdx.x] = b_edge[threadIdx.x];
    __syncthreads();

    // Wave-uniform MLP constants (compiler scalarizes these loads).
    float w1r[OUT_C], b1r[OUT_C], sr[OUT_C];
    float P = 0.f, Q = b2[0];
    #pragma unroll
    for (int j = 0; j < OUT_C; j++) {
        w1r[j] = w1[j];
        b1r[j] = b1[j];
        sr[j]  = 0.5f * w2[j];
        P = fmaf(w1r[j], sr[j], P);
        Q = fmaf(b1r[j], sr[j], Q);
    }

    int e = blockIdx.x * blockDim.x + threadIdx.x;
    if (e >= E) return;

    // Gather node features (64 B, 4x float4)
    const int c = col[e];
    const float4* hr = (const float4*)(h + (size_t)c * OUT_C);
    float4 h0 = hr[0], h1 = hr[1], h2 = hr[2], h3 = hr[3];
    float nv[16] = {h0.x, h0.y, h0.z, h0.w, h1.x, h1.y, h1.z, h1.w,
                    h2.x, h2.y, h2.z, h2.w, h3.x, h3.y, h3.z, h3.w};

    // Edge attributes (32 B, 2x float4)
    const float4* er = (const float4*)(edge_attr + (size_t)e * 8);
    float4 e0 = er[0], e1 = er[1];
    float ear[8] = {e0.x, e0.y, e0.z, e0.w, e1.x, e1.y, e1.z, e1.w};

    float sc[32];

    // Scores for the 16 node-feature scalars
    #pragma unroll
    for (int k = 0; k < 16; k++) {
        const float cv = nv[k];
        float acc = fmaf(P, cv, Q);
        #pragma unroll
        for (int j = 0; j < 16; j++) {
            float t = fmaf(cv, w1r[j], b1r[j]);
            acc = fmaf(fabsf(t), sr[j], acc);   // abs is a free input modifier
        }
        sc[k] = acc;
    }

    // ea transform + scores for the 16 edge-attr scalars
    #pragma unroll
    for (int j = 0; j < 16; j++) {
        float eaj = sbe[j];
        #pragma unroll
        for (int d = 0; d < 8; d++)
            eaj = fmaf(ear[d], sWe[d * 16 + j], eaj);
        float acc = fmaf(P, eaj, Q);
        #pragma unroll
        for (int jj = 0; jj < 16; jj++) {
            float t = fmaf(eaj, w1r[jj], b1r[jj]);
            acc = fmaf(fabsf(t), sr[jj], acc);
        }
        sc[16 + j] = acc;
    }

    // Softmax over the 32 scores (all in registers)
    float m = sc[0];
    #pragma unroll
    for (int i = 1; i < 32; i++) m = fmaxf(m, sc[i]);
    float sum = 0.f;
    #pragma unroll
    for (int i = 0; i < 32; i++) {
        sc[i] = __expf(sc[i] - m);
        sum += sc[i];
    }
    const float inv = 1.0f / sum;

    // out[e][i] = nv[i>>1] * attn[i]  (128 B contiguous per thread)
    float4* outr = (float4*)(out + (size_t)e * 32);
    #pragma unroll
    for (int q = 0; q < 8; q++) {
        float4 o;
        o.x = nv[(q * 4 + 0) >> 1] * sc[q * 4 + 0] * inv;
        o.y = nv[(q * 4 + 1) >> 1] * sc[q * 4 + 1] * inv;
        o.z = nv[(q * 4 + 2) >> 1] * sc[q * 4 + 2] * inv;
        o.w = nv[(q * 4 + 3) >> 1] * sc[q * 4 + 3] * inv;
        outr[q] = o;
    }
}

// ---------------------------------------------------------------------------
extern "C" void kernel_launch(void* const* d_in, const int* in_sizes, int n_in,
                              void* d_out, int out_size, void* d_ws, size_t ws_size,
                              hipStream_t stream) {
    const float* x         = (const float*)d_in[0];
    const float* edge_attr = (const float*)d_in[1];
    const int*   col       = (const int*)d_in[2];
    const float* W_lin     = (const float*)d_in[3];
    const float* b_lin     = (const float*)d_in[4];
    const float* W_edge    = (const float*)d_in[5];
    const float* b_edge    = (const float*)d_in[6];
    const float* w1        = (const float*)d_in[7];
    const float* b1        = (const float*)d_in[8];
    const float* w2        = (const float*)d_in[9];
    const float* b2        = (const float*)d_in[10];
    float* out = (float*)d_out;

    const int N = in_sizes[0] / IN_C;     // 100000
    const int E = in_sizes[1] / 8;        // 1000000

    float* h = (float*)d_ws;              // N*16 floats = 6.4 MB scratch

    dim3 blk(256);
    dim3 grid1((N + 255) / 256);
    node_linear_kernel<<<grid1, blk, 0, stream>>>(x, W_lin, b_lin, h, N);

    dim3 grid2((E + 255) / 256);
    edge_attn_kernel<<<grid2, blk, 0, stream>>>(edge_attr, col, h,
                                                W_edge, b_edge, w1, b1, w2, b2,
                                                out, E);
}

// Round 2
// 73.078 us; speedup vs baseline: 1.0739x; 1.0739x over previous
//
#include <hip/hip_runtime.h>
#include <math.h>

#define IN_C 64
#define OUT_C 16

// ---------------------------------------------------------------------------
// Kernel 1: h = x @ W_lin + b_lin      [N,64] x [64,16] -> [N,16]
// ---------------------------------------------------------------------------
__global__ __launch_bounds__(256) void node_linear_kernel(
    const float* __restrict__ x, const float* __restrict__ W_lin,
    const float* __restrict__ b_lin, float* __restrict__ h, int N)
{
    __shared__ float sW[IN_C * OUT_C];   // 4 KB
    __shared__ float sb[OUT_C];
    for (int i = threadIdx.x; i < IN_C * OUT_C; i += blockDim.x) sW[i] = W_lin[i];
    if (threadIdx.x < OUT_C) sb[threadIdx.x] = b_lin[threadIdx.x];
    __syncthreads();

    int n = blockIdx.x * blockDim.x + threadIdx.x;
    if (n >= N) return;

    float acc[OUT_C];
    #pragma unroll
    for (int j = 0; j < OUT_C; j++) acc[j] = sb[j];

    const float4* xr = (const float4*)(x + (size_t)n * IN_C);
    #pragma unroll
    for (int k4 = 0; k4 < IN_C / 4; k4++) {
        float4 xv = xr[k4];
        float xs[4] = {xv.x, xv.y, xv.z, xv.w};
        #pragma unroll
        for (int kk = 0; kk < 4; kk++) {
            const int k = k4 * 4 + kk;
            const float4* wrow = (const float4*)(sW + k * OUT_C);
            #pragma unroll
            for (int jq = 0; jq < 4; jq++) {
                float4 wv = wrow[jq];
                acc[jq * 4 + 0] = fmaf(xs[kk], wv.x, acc[jq * 4 + 0]);
                acc[jq * 4 + 1] = fmaf(xs[kk], wv.y, acc[jq * 4 + 1]);
                acc[jq * 4 + 2] = fmaf(xs[kk], wv.z, acc[jq * 4 + 2]);
                acc[jq * 4 + 3] = fmaf(xs[kk], wv.w, acc[jq * 4 + 3]);
            }
        }
    }

    float4* hr = (float4*)(h + (size_t)n * OUT_C);
    #pragma unroll
    for (int jq = 0; jq < 4; jq++) {
        float4 o;
        o.x = acc[jq * 4 + 0]; o.y = acc[jq * 4 + 1];
        o.z = acc[jq * 4 + 2]; o.w = acc[jq * 4 + 3];
        hr[jq] = o;
    }
}

// ---------------------------------------------------------------------------
// Kernel 2: per-edge fused pipeline, one thread per edge.
//   score(c) = P*c + Q + sum_j s_j * |c*w1_j + b1_j|   (abs-trick ReLU MLP)
// VALU discipline: w1 and Q forced into VGPRs so every inner fma has at most
// one SGPR operand (no compiler v_mov remat). b1/s stay scalar.
// ---------------------------------------------------------------------------
__global__ __launch_bounds__(256, 4) void edge_attn_kernel(
    const float* __restrict__ edge_attr, const int* __restrict__ col,
    const float* __restrict__ h,
    const float* __restrict__ W_edge, const float* __restrict__ b_edge,
    const float* __restrict__ w1, const float* __restrict__ b1,
    const float* __restrict__ w2, const float* __restrict__ b2,
    float* __restrict__ out, int E)
{
    __shared__ float sWe[8 * OUT_C];   // 512 B, row-major [8][16]
    if (threadIdx.x < 32)
        ((float4*)sWe)[threadIdx.x] = ((const float4*)W_edge)[threadIdx.x];
    __syncthreads();

    int e = blockIdx.x * blockDim.x + threadIdx.x;
    if (e >= E) return;

    // ---- issue global loads early -------------------------------------
    const int c = col[e];
    const float4* hr = (const float4*)(h + (size_t)c * OUT_C);
    float4 h0 = hr[0], h1 = hr[1], h2 = hr[2], h3 = hr[3];
    const float4* er = (const float4*)(edge_attr + (size_t)e * 8);
    float4 e0 = er[0], e1 = er[1];

    // ---- uniform MLP constants ----------------------------------------
    // w1v: VGPR (forced). b1u/su: uniform scalar (SGPR). P scalar, Q VGPR.
    float w1v[16], b1u[16], su[16];
    float P = 0.f, Qv;
    {
        float Q = b2[0];
        #pragma unroll
        for (int j = 0; j < 16; j++) {
            float w1j = w1[j];
            float b1j = b1[j];
            float sj  = 0.5f * w2[j];
            b1u[j] = b1j;
            su[j]  = sj;
            P = fmaf(w1j, sj, P);
            Q = fmaf(b1j, sj, Q);
            asm("v_mov_b32 %0, %1" : "=v"(w1v[j]) : "s"(w1j));
        }
        asm("v_mov_b32 %0, %1" : "=v"(Qv) : "s"(Q));
    }

    float nv[16] = {h0.x, h0.y, h0.z, h0.w, h1.x, h1.y, h1.z, h1.w,
                    h2.x, h2.y, h2.z, h2.w, h3.x, h3.y, h3.z, h3.w};
    float ear[8] = {e0.x, e0.y, e0.z, e0.w, e1.x, e1.y, e1.z, e1.w};

    // ---- ea = edge_attr @ W_edge + b_edge (float4 LDS reads) ----------
    float ea[16];
    #pragma unroll
    for (int jq = 0; jq < 4; jq++) {
        float4 w[8];
        #pragma unroll
        for (int d = 0; d < 8; d++)
            w[d] = ((const float4*)sWe)[d * 4 + jq];
        #pragma unroll
        for (int cc = 0; cc < 4; cc++) {
            const float* wc0 = (const float*)&w[0];
            // bias folded into the first fma (b_edge is the 1 SGPR operand)
            float acc = fmaf(ear[0], ((const float*)&w[0])[cc], b_edge[jq * 4 + cc]);
            #pragma unroll
            for (int d = 1; d < 8; d++)
                acc = fmaf(ear[d], ((const float*)&w[d])[cc], acc);
            ea[jq * 4 + cc] = acc;
            (void)wc0;
        }
    }

    // ---- 32 scores ----------------------------------------------------
    float sc[32];
    #pragma unroll
    for (int k = 0; k < 16; k++) {
        const float cv = nv[k];
        float acc = fmaf(P, cv, Qv);                 // s,v,v : 1 SGPR
        #pragma unroll
        for (int j = 0; j < 16; j++) {
            float t = fmaf(cv, w1v[j], b1u[j]);      // v,v,s : 1 SGPR
            acc = fmaf(fabsf(t), su[j], acc);        // |v|,s,v : 1 SGPR
        }
        sc[k] = acc;
    }
    #pragma unroll
    for (int k = 0; k < 16; k++) {
        const float cv = ea[k];
        float acc = fmaf(P, cv, Qv);
        #pragma unroll
        for (int j = 0; j < 16; j++) {
            float t = fmaf(cv, w1v[j], b1u[j]);
            acc = fmaf(fabsf(t), su[j], acc);
        }
        sc[16 + k] = acc;
    }

    // ---- softmax over 32 (registers) ----------------------------------
    float m01 = fmaxf(sc[0], sc[1]);
    #pragma unroll
    for (int i = 2; i < 32; i++) m01 = fmaxf(m01, sc[i]);
    float sum = 0.f;
    #pragma unroll
    for (int i = 0; i < 32; i++) {
        sc[i] = __expf(sc[i] - m01);
        sum += sc[i];
    }
    const float inv = 1.0f / sum;

    // ---- output: out[e][i] = nv[i>>1] * attn[i] -----------------------
    float nvs[16];
    #pragma unroll
    for (int k = 0; k < 16; k++) nvs[k] = nv[k] * inv;

    float4* outr = (float4*)(out + (size_t)e * 32);
    #pragma unroll
    for (int q = 0; q < 8; q++) {
        float4 o;
        o.x = nvs[(q * 4 + 0) >> 1] * sc[q * 4 + 0];
        o.y = nvs[(q * 4 + 1) >> 1] * sc[q * 4 + 1];
        o.z = nvs[(q * 4 + 2) >> 1] * sc[q * 4 + 2];
        o.w = nvs[(q * 4 + 3) >> 1] * sc[q * 4 + 3];
        outr[q] = o;
    }
}

// ---------------------------------------------------------------------------
extern "C" void kernel_launch(void* const* d_in, const int* in_sizes, int n_in,
                              void* d_out, int out_size, void* d_ws, size_t ws_size,
                              hipStream_t stream) {
    const float* x         = (const float*)d_in[0];
    const float* edge_attr = (const float*)d_in[1];
    const int*   col       = (const int*)d_in[2];
    const float* W_lin     = (const float*)d_in[3];
    const float* b_lin     = (const float*)d_in[4];
    const float* W_edge    = (const float*)d_in[5];
    const float* b_edge    = (const float*)d_in[6];
    const float* w1        = (const float*)d_in[7];
    const float* b1        = (const float*)d_in[8];
    const float* w2        = (const float*)d_in[9];
    const float* b2        = (const float*)d_in[10];
    float* out = (float*)d_out;

    const int N = in_sizes[0] / IN_C;     // 100000
    const int E = in_sizes[1] / 8;        // 1000000

    float* h = (float*)d_ws;              // N*16 floats = 6.4 MB scratch

    dim3 blk(256);
    dim3 grid1((N + 255) / 256);
    node_linear_kernel<<<grid1, blk, 0, stream>>>(x, W_lin, b_lin, h, N);

    dim3 grid2((E + 255) / 256);
    edge_attn_kernel<<<grid2, blk, 0, stream>>>(edge_attr, col, h,
                                                W_edge, b_edge, w1, b1, w2, b2,
                                                out, E);
}